// Round 2
// baseline (2471.202 us; speedup 1.0000x reference)
//
#include <hip/hip_runtime.h>
#include <hip/hip_bf16.h>
#include <math.h>

// Problem constants
#define N_B    256   // batch
#define L_SEQ  512   // sequence length
#define HID    512   // hidden
#define EMB_D  256   // embedding dim

// 16 groups x 16 batch rows; 8 wgs/group each owning 64 Whh cols.
#define NGROUPS 16
#define GWGS    8

// Workspace: E_sw + exchange (parity dbuf) [+ optional 4KB control region,
// used ONLY if ws_size proves it fits].
#define ESW_SHORTS_PER_BLK 8192   // per (g,t): 2 planes x 8 kk x 64 lanes x 8 = 16 KB
#define ESW_BYTES  ((size_t)NGROUPS * L_SEQ * ESW_SHORTS_PER_BLK * 2)  // 134,217,728
#define EX_UINTS_PER_SLOT (16 * HID)                                   // 8192 = 32 KB
#define EX_BYTES   ((size_t)2 * NGROUPS * EX_UINTS_PER_SLOT * 4)       // 1 MB
#define CTL_BYTES  4096

typedef short v8s __attribute__((ext_vector_type(8)));   // 8 bf16 MFMA A/B frag
typedef float v4f __attribute__((ext_vector_type(4)));   // MFMA C/D frag

static __device__ __forceinline__ unsigned short bf_bits(__hip_bfloat16 h) {
    union { __hip_bfloat16 b; unsigned short u; } c; c.b = h; return c.u;
}
static __device__ __forceinline__ void split_hilo(float v, short& hi, short& lo) {
    const __hip_bfloat16 h = __float2bfloat16(v);
    hi = (short)bf_bits(h);
    lo = (short)bf_bits(__float2bfloat16(v - __bfloat162float(h)));
}
static __device__ __forceinline__ void cvt8_hilo(const float* __restrict__ p,
                                                 v8s& hi, v8s& lo) {
    #pragma unroll
    for (int i = 0; i < 8; ++i) { short h, l; split_hilo(p[i], h, l); hi[i] = h; lo[i] = l; }
}
// async global->LDS, 16 B per lane; LDS dest = wave-uniform base + lane*16
static __device__ __forceinline__ void gl_lds16(const short* g, short* l) {
    __builtin_amdgcn_global_load_lds(
        (const __attribute__((address_space(1))) unsigned int*)g,
        (__attribute__((address_space(3))) unsigned int*)l, 16, 0, 0);
}
// fast tanh: 1 - 2/(exp(2x)+1); v_exp_f32-based, ~1e-7 abs err
static __device__ __forceinline__ float tanh_fast(float x) {
    const float z = __expf(2.0f * x);
    return 1.0f - 2.0f / (z + 1.0f);
}

// ---- exchange-op flavors -------------------------------------------------
// sc1 path (device scope, LLC): correct for any WG->XCD placement (R0-proven).
static __device__ __forceinline__ void st_sc1(unsigned int* p, unsigned int v) {
    __hip_atomic_store(p, v, __ATOMIC_RELAXED, __HIP_MEMORY_SCOPE_AGENT);
}
static __device__ __forceinline__ unsigned int ld_sc1(const unsigned int* p) {
    return __hip_atomic_load(p, __ATOMIC_RELAXED, __HIP_MEMORY_SCOPE_AGENT);
}
// sc0 load: bypass L1, served by this XCD's L2 (same-XCD coherence point).
static __device__ __forceinline__ unsigned int ld_sc0(const unsigned int* p) {
    unsigned int v;
    asm volatile("global_load_dword %0, %1, off sc0\n\ts_waitcnt vmcnt(0)"
                 : "=v"(v) : "v"(p) : "memory");
    return v;
}
// plain store: lands dirty in the producing XCD's L2 (no HBM write-through).
static __device__ __forceinline__ void st_plain(unsigned int* p, unsigned int v) {
    asm volatile("global_store_dword %0, %1, off" :: "v"(p), "v"(v) : "memory");
}

// ---------------------------------------------------------------------------
// Precompute E_sw (unchanged, correctness-proven).
// ---------------------------------------------------------------------------
__global__ __launch_bounds__(256) void esw_build(
    const int* __restrict__ X, const float* __restrict__ emb,
    short* __restrict__ Esw)
{
    const int bid = blockIdx.x;           // g*512 + t
    const int g = bid >> 9, t = bid & 511;
    short* base = Esw + (size_t)bid * ESW_SHORTS_PER_BLK;
    #pragma unroll
    for (int h = 0; h < 2; ++h) {
        const int f    = threadIdx.x + h * 256;   // frag id 0..511
        const int kk   = f >> 6, lane = f & 63;
        const int m    = lane & 15, qp = lane >> 4;
        const int idx  = X[(g * 16 + m) * L_SEQ + t];
        const float* src = emb + (size_t)idx * EMB_D + kk * 32 + qp * 8;
        v8s hi8, lo8;
        cvt8_hilo(src, hi8, lo8);
        short* d = base + (size_t)(kk * 64 + lane) * 8;
        *(v8s*)d          = hi8;
        *(v8s*)(d + 4096) = lo8;
    }
}

// ---------------------------------------------------------------------------
// Persistent RNN scan — structure byte-identical to the proven R0 kernel.
// Self-validating exchange (epoch tag in bit16 of every word); identical
// protocol on both paths, only the cache-op flavor differs:
//   FAST (group verified same-XCD via id check + two-round visibility
//         handshake): publish = plain store (dirty in shared L2),
//         poll = dwordx2 sc0 (L1-bypass, L2-hit) -> ~250cy RTT.
//   SLOW: agent-scope sc1 (R0 behavior, correct under any placement).
// ---------------------------------------------------------------------------
template<bool FAST>
static __device__ __forceinline__ void scan_loop(
    const float* __restrict__ Whh, const float* __restrict__ Whh_b,
    const float* __restrict__ Wxh, const float* __restrict__ Wxh_b,
    const short* __restrict__ Esw, unsigned int* __restrict__ ex,
    float* __restrict__ out, short* __restrict__ ldsbuf,
    unsigned int (*__restrict__ tp)[256], const int g, const int j, const int tid)
{
    const int w    = tid >> 6;
    const int l    = tid & 63;
    const int lo16 = l & 15;
    const int q    = l >> 4;
    const int cbase = j * 64 + w * 16;
    const int nbase = g * 16;

    short* lds_h = ldsbuf;          // P*16384 + plane*8192 + (kk*64+l)*8 + i
    short* lds_e = ldsbuf + 32768;  // P*8192  + plane*4096 + (kk*64+l)*8 + i

    // Whh 64-col slice as hi/lo bf16 B-frags
    v8s bhi[16], blo[16];
    {
        const float* wp = Whh + (long)(cbase + lo16) * HID + q * 8;
        #pragma unroll
        for (int kk = 0; kk < 16; ++kk) cvt8_hilo(wp + kk * 32, bhi[kk], blo[kk]);
    }
    // Wxh 64-col slice
    v8s xhi[8], xlo[8];
    {
        const float* wp = Wxh + (long)(cbase + lo16) * EMB_D + q * 8;
        #pragma unroll
        for (int kk = 0; kk < 8; ++kk) cvt8_hilo(wp + kk * 32, xhi[kk], xlo[kk]);
    }
    const int hcol = cbase + lo16;
    const float bias = Whh_b[hcol] + Wxh_b[hcol];

    // wave's contiguous 1 KB publish region (uints)
    const int region = (2 * j + (w >> 1)) * 512 + (w & 1) * 256;

    unsigned int* ex0 = ex + (size_t)g * EX_UINTS_PER_SLOT;              // parity 0
    unsigned int* ex1 = ex + (size_t)(NGROUPS + g) * EX_UINTS_PER_SLOT;  // parity 1
    const short* esrc = Esw + (size_t)(g * 512) * ESW_SHORTS_PER_BLK;

    // preamble: stage E(0) into parity-0 E buffer; barrier makes it visible
    #pragma unroll
    for (int c = 0; c < 4; ++c)
        gl_lds16(esrc + (w * 4 + c) * 512 + l * 8, lds_e + (w * 4 + c) * 512);
    __syncthreads();

    for (int t = 0; t < L_SEQ; ++t) {
        const int P = t & 1;
        short* lh = lds_h + P * 16384;
        short* le = lds_e + P * 8192;
        unsigned int* exsrc = P ? ex1 : ex0;
        unsigned int* exdst = P ? ex0 : ex1;

        // (0) prefetch E(t+1) into other parity (drained by this step's
        // barrier; its HBM latency overlaps the poll's wait-for-peers time)
        if (t + 1 < L_SEQ) {
            const short* eb = esrc + (size_t)(t + 1) * ESW_SHORTS_PER_BLK;
            short* leN = lds_e + (P ^ 1) * 8192;
            #pragma unroll
            for (int c = 0; c < 4; ++c)
                gl_lds16(eb + (w * 4 + c) * 512 + l * 8, leN + (w * 4 + c) * 512);
        }

        // (1) E MFMAs (peer-independent; run while peers' h data propagates)
        v4f acc0 = {0,0,0,0}, acc1 = {0,0,0,0}, acc2 = {0,0,0,0};
        #pragma unroll
        for (int kk = 0; kk < 8; ++kk) {
            v8s ah = *(const v8s*)(le + (kk * 64 + l) * 8);
            v8s al = *(const v8s*)(le + 4096 + (kk * 64 + l) * 8);
            acc0 = __builtin_amdgcn_mfma_f32_16x16x32_bf16(ah, xhi[kk], acc0, 0, 0, 0);
            acc1 = __builtin_amdgcn_mfma_f32_16x16x32_bf16(ah, xlo[kk], acc1, 0, 0, 0);
            acc2 = __builtin_amdgcn_mfma_f32_16x16x32_bf16(al, xhi[kk], acc2, 0, 0, 0);
        }

        // (2) tag-poll h: reload own 16 u64 until every word's bit16 == read tag.
        unsigned long long hv64[16];
        {
            const unsigned long long* hs = (const unsigned long long*)exsrc;
            const unsigned long long tagmask = 0x0001000000010000ull;
            const unsigned long long want = ((t >> 1) & 1) ? tagmask : 0ull;
            if (FAST) {
                for (;;) {
                    #pragma unroll
                    for (int s = 0; s < 16; ++s)
                        asm volatile("global_load_dwordx2 %0, %1, off sc0"
                                     : "=v"(hv64[s]) : "v"(hs + s * 256 + tid));
                    asm volatile("s_waitcnt vmcnt(0)" ::: "memory");
                    __builtin_amdgcn_sched_barrier(0);   // rule 18: pin check after wait
                    unsigned long long bad = 0;
                    #pragma unroll
                    for (int s = 0; s < 16; ++s) bad |= (hv64[s] ^ want) & tagmask;
                    if (__all(bad == 0)) break;
                }
            } else {
                for (;;) {
                    #pragma unroll
                    for (int s = 0; s < 16; ++s)
                        hv64[s] = __hip_atomic_load(hs + s * 256 + tid,
                                                    __ATOMIC_RELAXED,
                                                    __HIP_MEMORY_SCOPE_AGENT);
                    unsigned long long bad = 0;
                    #pragma unroll
                    for (int s = 0; s < 16; ++s) bad |= (hv64[s] ^ want) & tagmask;
                    if (__all(bad == 0)) break;
                }
            }
        }

        // (3) unpack h -> LDS planes (lane stride 1 u32: conflict-free)
        {
            unsigned int* lh_hi = (unsigned int*)lh;
            unsigned int* lh_lo = lh_hi + 4096;
            #pragma unroll
            for (int s = 0; s < 16; ++s) {
                const int o = s * 256 + tid;
                const unsigned int w0 = (unsigned int)hv64[s];
                const unsigned int w1 = (unsigned int)(hv64[s] >> 32);
                lh_hi[o] = (w0 & 0xffffu) | (w1 << 16);
                lh_lo[o] = (w0 >> 16)     | (w1 & 0xffff0000u);
            }
        }
        __syncthreads();   // the step's ONLY barrier: h LDS + E(t+1) staged

        // (4) h MFMAs (K=512)
        #pragma unroll
        for (int kk = 0; kk < 16; ++kk) {
            v8s ah = *(const v8s*)(lh + (kk * 64 + l) * 8);
            v8s al = *(const v8s*)(lh + 8192 + (kk * 64 + l) * 8);
            acc0 = __builtin_amdgcn_mfma_f32_16x16x32_bf16(ah, bhi[kk], acc0, 0, 0, 0);
            acc1 = __builtin_amdgcn_mfma_f32_16x16x32_bf16(ah, blo[kk], acc1, 0, 0, 0);
            acc2 = __builtin_amdgcn_mfma_f32_16x16x32_bf16(al, bhi[kk], acc2, 0, 0, 0);
        }

        // (5) epilogue: tanh, split, embed write tag in bit16, transpose via
        //     LDS scratch, 4 fully coalesced stores.
        if (t < L_SEQ - 1) {
            const unsigned int wtag = (unsigned int)(((t + 1) >> 1) & 1) << 16;
            unsigned int* myt = tp[w];
            #pragma unroll
            for (int r = 0; r < 4; ++r) {
                const int m = q * 4 + r;             // C/D: row=(lane>>4)*4+r
                const float pre = acc0[r] + acc1[r] + acc2[r] + bias;
                const float hv = tanh_fast(pre);
                short hi, lo; split_hilo(hv, hi, lo);
                unsigned int word = (unsigned int)(unsigned short)hi
                                  | ((unsigned int)(unsigned short)lo << 16);
                word = (word & 0xFFFEFFFFu) | wtag;   // lo-LSB := epoch tag
                myt[(m + 16 * (lo16 >> 3)) * 8 + (lo16 & 7)] = word;
            }
            asm volatile("s_waitcnt lgkmcnt(0)" ::: "memory");
            #pragma unroll
            for (int k = 0; k < 4; ++k) {
                const unsigned int val = tp[w][k * 64 + l];
                unsigned int* p = exdst + region + k * 64 + l;
                if (FAST) st_plain(p, val);
                else      st_sc1(p, val);
            }
        } else {
            #pragma unroll
            for (int r = 0; r < 4; ++r) {
                const int m = q * 4 + r;
                const float pre = acc0[r] + acc1[r] + acc2[r] + bias;
                out[(long)(nbase + m) * HID + hcol] = tanh_fast(pre);
            }
        }
    }
}

__global__ __launch_bounds__(256, 1) void rnn_scan7(
    const float* __restrict__ Whh,
    const float* __restrict__ Whh_b,
    const float* __restrict__ Wxh,
    const float* __restrict__ Wxh_b,
    const short* __restrict__ Esw,
    unsigned int* __restrict__ ex,
    unsigned int* __restrict__ ctl,   // may be nullptr -> slow path
    float* __restrict__ out)
{
    const int bid = blockIdx.x;
    const int g   = bid & 15;    // group
    const int j   = bid >> 4;    // member 0..7
    const int tid = threadIdx.x;

    __shared__ short ldsbuf[49152];          // h dbuf 64 KB + E dbuf 32 KB
    __shared__ unsigned int tp[4][256];      // 4 KB transpose scratch
    __shared__ int s_fast;

    // ---- runtime same-XCD detection + two-round sc0 visibility handshake.
    // All unbounded spins use the R0-proven sc1 flavor; the only sc0 spins
    // carry a hard iteration budget (deterministic fall-through to slow).
    if (tid == 0) {
        int allok = 0;
        if (ctl != nullptr) {
            unsigned int* det  = ctl;         // [128] xcc ids   (init 0xFF)
            unsigned int* tokA = ctl + 128;   // [128] round A   (init 0xFF)
            unsigned int* tokB = ctl + 256;   // [128] round B   (init 0xFF)
            unsigned int* prm  = ctl + 384;   // [128] primed    (init 0xFF)
            unsigned int* vot  = ctl + 512;   // [128] votes     (init 0xFF)
            unsigned int xcc;
            asm volatile("s_getreg_b32 %0, hwreg(HW_REG_XCC_ID)" : "=s"(xcc));
            st_sc1(det + bid, 0x100u | (xcc & 0xffu));
            unsigned int ids[8];
            for (int jj = 0; jj < 8; ++jj) {
                unsigned int v;
                do { v = ld_sc1(det + jj * 16 + g); } while (v == 0xFFFFFFFFu);
                ids[jj] = v;
            }
            bool same = true;
            for (int jj = 1; jj < 8; ++jj) same &= (ids[jj] == ids[0]);
            int ok = 0;
            if (same) {
                // prime: pull token lines into this L2 as stale copies; a
                // cross-XCD pairing then spins on them forever (bounded).
                for (int jj = 0; jj < 8; ++jj) {
                    (void)ld_sc0(tokA + jj * 16 + g);
                    (void)ld_sc0(tokB + jj * 16 + g);
                }
                st_sc1(prm + bid, 1u);
                for (int jj = 0; jj < 8; ++jj)
                    while (ld_sc1(prm + jj * 16 + g) == 0xFFFFFFFFu) {}
                int budget = 1 << 13;
                st_plain(tokA + bid, 0xA5A5A5A5u);
                ok = 1;
                for (int jj = 0; jj < 8 && ok; ++jj) {
                    unsigned int v;
                    do { v = ld_sc0(tokA + jj * 16 + g); }
                    while (v != 0xA5A5A5A5u && --budget > 0);
                    if (v != 0xA5A5A5A5u) ok = 0;
                }
                if (ok) {
                    st_plain(tokB + bid, 0x5A5A5A5Au);
                    for (int jj = 0; jj < 8 && ok; ++jj) {
                        unsigned int v;
                        do { v = ld_sc0(tokB + jj * 16 + g); }
                        while (v != 0x5A5A5A5Au && --budget > 0);
                        if (v != 0x5A5A5A5Au) ok = 0;
                    }
                }
            }
            st_sc1(vot + bid, ok ? 2u : 1u);
            allok = 1;
            for (int jj = 0; jj < 8; ++jj) {
                unsigned int v;
                do { v = ld_sc1(vot + jj * 16 + g); } while (v == 0xFFFFFFFFu);
                allok &= (v == 2u) ? 1 : 0;
            }
        }
        s_fast = allok;
    }
    __syncthreads();

    if (s_fast)
        scan_loop<true >(Whh, Whh_b, Wxh, Wxh_b, Esw, ex, out, ldsbuf, tp, g, j, tid);
    else
        scan_loop<false>(Whh, Whh_b, Wxh, Wxh_b, Esw, ex, out, ldsbuf, tp, g, j, tid);
}

// ---------------------------------------------------------------------------
extern "C" void kernel_launch(void* const* d_in, const int* in_sizes, int n_in,
                              void* d_out, int out_size, void* d_ws, size_t ws_size,
                              hipStream_t stream) {
    const int*   X     = (const int*)d_in[0];
    const float* emb   = (const float*)d_in[1];
    const float* Whh   = (const float*)d_in[2];
    const float* Whh_b = (const float*)d_in[3];
    const float* Wxh   = (const float*)d_in[4];
    const float* Wxh_b = (const float*)d_in[5];

    char* ws = (char*)d_ws;
    short*        Esw = (short*)ws;
    unsigned int* ex  = (unsigned int*)(ws + ESW_BYTES);
    // ctl only exists if the workspace provably fits it (R0 only proved
    // [0, ESW+EX) writable); otherwise the kernel runs the proven slow path.
    unsigned int* ctl = nullptr;
    if (ws_size >= ESW_BYTES + EX_BYTES + CTL_BYTES)
        ctl = (unsigned int*)(ws + ESW_BYTES + EX_BYTES);

    // parity 0 := 0x00 (h(0)=0, tag 0 matches t=0 immediately);
    // parity 1 := 0xFF (tag 1 blocks t=1 until step-0 data lands);
    // ctl      := 0xFF (detect/handshake slots empty).
    hipMemsetAsync(ex, 0x00, EX_BYTES / 2, stream);
    hipMemsetAsync((char*)ex + EX_BYTES / 2, 0xFF, EX_BYTES / 2, stream);
    if (ctl) hipMemsetAsync(ctl, 0xFF, CTL_BYTES, stream);

    esw_build<<<dim3(NGROUPS * L_SEQ), dim3(256), 0, stream>>>(X, emb, Esw);
    rnn_scan7<<<dim3(NGROUPS * GWGS), dim3(256), 0, stream>>>(
        Whh, Whh_b, Wxh, Wxh_b, Esw, ex, ctl, (float*)d_out);
}

// Round 3
// 2063.102 us; speedup vs baseline: 1.1978x; 1.1978x over previous
//
#include <hip/hip_runtime.h>
#include <hip/hip_bf16.h>
#include <math.h>

// Problem constants
#define N_B    256   // batch
#define L_SEQ  512   // sequence length
#define HID    512   // hidden
#define EMB_D  256   // embedding dim

// 16 groups x 16 batch rows; 8 wgs/group each owning 64 Whh cols.
#define NGROUPS 16
#define GWGS    8

// Workspace: E_sw + exchange (parity dbuf) [+ optional 4KB control region].
#define ESW_SHORTS_PER_BLK 8192   // per (g,t): 2 planes x 8 kk x 64 lanes x 8 = 16 KB
#define ESW_BYTES  ((size_t)NGROUPS * L_SEQ * ESW_SHORTS_PER_BLK * 2)  // 134,217,728
#define EX_UINTS_PER_SLOT (16 * HID)                                   // 8192 = 32 KB
#define EX_BYTES   ((size_t)2 * NGROUPS * EX_UINTS_PER_SLOT * 4)       // 1 MB
#define CTL_BYTES  4096

typedef short v8s __attribute__((ext_vector_type(8)));   // 8 bf16 MFMA A/B frag
typedef float v4f __attribute__((ext_vector_type(4)));   // MFMA C/D frag

static __device__ __forceinline__ unsigned short bf_bits(__hip_bfloat16 h) {
    union { __hip_bfloat16 b; unsigned short u; } c; c.b = h; return c.u;
}
static __device__ __forceinline__ void split_hilo(float v, short& hi, short& lo) {
    const __hip_bfloat16 h = __float2bfloat16(v);
    hi = (short)bf_bits(h);
    lo = (short)bf_bits(__float2bfloat16(v - __bfloat162float(h)));
}
static __device__ __forceinline__ void cvt8_hilo(const float* __restrict__ p,
                                                 v8s& hi, v8s& lo) {
    #pragma unroll
    for (int i = 0; i < 8; ++i) { short h, l; split_hilo(p[i], h, l); hi[i] = h; lo[i] = l; }
}
// async global->LDS, 16 B per lane; LDS dest = wave-uniform base + lane*16
static __device__ __forceinline__ void gl_lds16(const short* g, short* l) {
    __builtin_amdgcn_global_load_lds(
        (const __attribute__((address_space(1))) unsigned int*)g,
        (__attribute__((address_space(3))) unsigned int*)l, 16, 0, 0);
}
// fast tanh: 1 - 2/(exp(2x)+1); v_exp_f32-based, ~1e-7 abs err
static __device__ __forceinline__ float tanh_fast(float x) {
    const float z = __expf(2.0f * x);
    return 1.0f - 2.0f / (z + 1.0f);
}

// ---- exchange-op flavors -------------------------------------------------
// sc1 (device scope via LLC): correct for any WG->XCD placement (R0-proven).
static __device__ __forceinline__ void st_sc1(unsigned int* p, unsigned int v) {
    __hip_atomic_store(p, v, __ATOMIC_RELAXED, __HIP_MEMORY_SCOPE_AGENT);
}
static __device__ __forceinline__ unsigned int ld_sc1(const unsigned int* p) {
    return __hip_atomic_load(p, __ATOMIC_RELAXED, __HIP_MEMORY_SCOPE_AGENT);
}
// sc0 load: intended L1-bypass, served by this XCD's L2.
static __device__ __forceinline__ unsigned int ld_sc0(const unsigned int* p) {
    unsigned int v;
    asm volatile("global_load_dword %0, %1, off sc0\n\ts_waitcnt vmcnt(0)"
                 : "=v"(v) : "v"(p) : "memory");
    return v;
}
// sc0 store: SE-scope write -> write-through L1 into L2 (no LLC/HBM push).
static __device__ __forceinline__ void st_sc0g(unsigned int* p, unsigned int v) {
    asm volatile("global_store_dword %0, %1, off sc0" :: "v"(p), "v"(v) : "memory");
}
// L2-local atomics (no sc1): execute at this XCD's L2, L1-proof by nature.
static __device__ __forceinline__ void at_xchg32(unsigned int* p, unsigned int v) {
    (void)__hip_atomic_exchange(p, v, __ATOMIC_RELAXED, __HIP_MEMORY_SCOPE_WORKGROUP);
}
static __device__ __forceinline__ unsigned int at_or32(unsigned int* p) {
    return __hip_atomic_fetch_or(p, 0u, __ATOMIC_RELAXED, __HIP_MEMORY_SCOPE_WORKGROUP);
}
static __device__ __forceinline__ unsigned long long at_or64(unsigned long long* p) {
    return __hip_atomic_fetch_or(p, 0ull, __ATOMIC_RELAXED, __HIP_MEMORY_SCOPE_WORKGROUP);
}

// ---------------------------------------------------------------------------
// Precompute E_sw (unchanged, correctness-proven).
// ---------------------------------------------------------------------------
__global__ __launch_bounds__(256) void esw_build(
    const int* __restrict__ X, const float* __restrict__ emb,
    short* __restrict__ Esw)
{
    const int bid = blockIdx.x;           // g*512 + t
    const int g = bid >> 9, t = bid & 511;
    short* base = Esw + (size_t)bid * ESW_SHORTS_PER_BLK;
    #pragma unroll
    for (int h = 0; h < 2; ++h) {
        const int f    = threadIdx.x + h * 256;   // frag id 0..511
        const int kk   = f >> 6, lane = f & 63;
        const int m    = lane & 15, qp = lane >> 4;
        const int idx  = X[(g * 16 + m) * L_SEQ + t];
        const float* src = emb + (size_t)idx * EMB_D + kk * 32 + qp * 8;
        v8s hi8, lo8;
        cvt8_hilo(src, hi8, lo8);
        short* d = base + (size_t)(kk * 64 + lane) * 8;
        *(v8s*)d          = hi8;
        *(v8s*)(d + 4096) = lo8;
    }
}

// ---------------------------------------------------------------------------
// Persistent RNN scan — structure byte-identical to the proven R0 kernel.
// Self-validating exchange (epoch tag in bit16 of EVERY u32 word); identical
// protocol on all paths, only the cache-op flavor differs:
//   FLAVOR 1: publish = global_store sc0 (write-through L1 -> shared L2),
//             poll    = global_load_dwordx2 sc0 (L1-bypass, L2-hit).
//   FLAVOR 2: publish = L2-local atomic_exchange (u32),
//             poll    = L2-local atomic_fetch_or(0) (u64) — L1-proof.
//   FLAVOR 0: agent-scope sc1 (R0 behavior, correct under any placement).
// Torn u64 reads are benign: each u32 half carries the epoch tag.
// ---------------------------------------------------------------------------
template<int FLAVOR>
static __device__ __forceinline__ void scan_loop(
    const float* __restrict__ Whh, const float* __restrict__ Whh_b,
    const float* __restrict__ Wxh, const float* __restrict__ Wxh_b,
    const short* __restrict__ Esw, unsigned int* __restrict__ ex,
    float* __restrict__ out, short* __restrict__ ldsbuf,
    unsigned int (*__restrict__ tp)[256], const int g, const int j, const int tid)
{
    const int w    = tid >> 6;
    const int l    = tid & 63;
    const int lo16 = l & 15;
    const int q    = l >> 4;
    const int cbase = j * 64 + w * 16;
    const int nbase = g * 16;

    short* lds_h = ldsbuf;          // P*16384 + plane*8192 + (kk*64+l)*8 + i
    short* lds_e = ldsbuf + 32768;  // P*8192  + plane*4096 + (kk*64+l)*8 + i

    // Whh 64-col slice as hi/lo bf16 B-frags
    v8s bhi[16], blo[16];
    {
        const float* wp = Whh + (long)(cbase + lo16) * HID + q * 8;
        #pragma unroll
        for (int kk = 0; kk < 16; ++kk) cvt8_hilo(wp + kk * 32, bhi[kk], blo[kk]);
    }
    // Wxh 64-col slice
    v8s xhi[8], xlo[8];
    {
        const float* wp = Wxh + (long)(cbase + lo16) * EMB_D + q * 8;
        #pragma unroll
        for (int kk = 0; kk < 8; ++kk) cvt8_hilo(wp + kk * 32, xhi[kk], xlo[kk]);
    }
    const int hcol = cbase + lo16;
    const float bias = Whh_b[hcol] + Wxh_b[hcol];

    // wave's contiguous 1 KB publish region (uints)
    const int region = (2 * j + (w >> 1)) * 512 + (w & 1) * 256;

    unsigned int* ex0 = ex + (size_t)g * EX_UINTS_PER_SLOT;              // parity 0
    unsigned int* ex1 = ex + (size_t)(NGROUPS + g) * EX_UINTS_PER_SLOT;  // parity 1
    const short* esrc = Esw + (size_t)(g * 512) * ESW_SHORTS_PER_BLK;

    // preamble: stage E(0) into parity-0 E buffer; barrier makes it visible
    #pragma unroll
    for (int c = 0; c < 4; ++c)
        gl_lds16(esrc + (w * 4 + c) * 512 + l * 8, lds_e + (w * 4 + c) * 512);
    __syncthreads();

    for (int t = 0; t < L_SEQ; ++t) {
        const int P = t & 1;
        short* lh = lds_h + P * 16384;
        short* le = lds_e + P * 8192;
        unsigned int* exsrc = P ? ex1 : ex0;
        unsigned int* exdst = P ? ex0 : ex1;

        // (0) prefetch E(t+1) into other parity (drained by this step's
        // barrier; its HBM latency overlaps the poll's wait-for-peers time)
        if (t + 1 < L_SEQ) {
            const short* eb = esrc + (size_t)(t + 1) * ESW_SHORTS_PER_BLK;
            short* leN = lds_e + (P ^ 1) * 8192;
            #pragma unroll
            for (int c = 0; c < 4; ++c)
                gl_lds16(eb + (w * 4 + c) * 512 + l * 8, leN + (w * 4 + c) * 512);
        }

        // (1) E MFMAs (peer-independent; run while peers' h data propagates)
        v4f acc0 = {0,0,0,0}, acc1 = {0,0,0,0}, acc2 = {0,0,0,0};
        #pragma unroll
        for (int kk = 0; kk < 8; ++kk) {
            v8s ah = *(const v8s*)(le + (kk * 64 + l) * 8);
            v8s al = *(const v8s*)(le + 4096 + (kk * 64 + l) * 8);
            acc0 = __builtin_amdgcn_mfma_f32_16x16x32_bf16(ah, xhi[kk], acc0, 0, 0, 0);
            acc1 = __builtin_amdgcn_mfma_f32_16x16x32_bf16(ah, xlo[kk], acc1, 0, 0, 0);
            acc2 = __builtin_amdgcn_mfma_f32_16x16x32_bf16(al, xhi[kk], acc2, 0, 0, 0);
        }

        // (2) tag-poll h: reload own 16 u64 until every word's bit16 == read tag.
        unsigned long long hv64[16];
        {
            const unsigned long long tagmask = 0x0001000000010000ull;
            const unsigned long long want = ((t >> 1) & 1) ? tagmask : 0ull;
            if (FLAVOR == 1) {
                const unsigned long long* hs = (const unsigned long long*)exsrc;
                for (;;) {
                    #pragma unroll
                    for (int s = 0; s < 16; ++s)
                        asm volatile("global_load_dwordx2 %0, %1, off sc0"
                                     : "=v"(hv64[s]) : "v"(hs + s * 256 + tid));
                    asm volatile("s_waitcnt vmcnt(0)" ::: "memory");
                    __builtin_amdgcn_sched_barrier(0);   // rule 18: pin check after wait
                    unsigned long long bad = 0;
                    #pragma unroll
                    for (int s = 0; s < 16; ++s) bad |= (hv64[s] ^ want) & tagmask;
                    if (__all(bad == 0)) break;
                }
            } else if (FLAVOR == 2) {
                unsigned long long* hs = (unsigned long long*)exsrc;
                for (;;) {
                    #pragma unroll
                    for (int s = 0; s < 16; ++s)
                        hv64[s] = at_or64(hs + s * 256 + tid);
                    unsigned long long bad = 0;
                    #pragma unroll
                    for (int s = 0; s < 16; ++s) bad |= (hv64[s] ^ want) & tagmask;
                    if (__all(bad == 0)) break;
                }
            } else {
                const unsigned long long* hs = (const unsigned long long*)exsrc;
                for (;;) {
                    #pragma unroll
                    for (int s = 0; s < 16; ++s)
                        hv64[s] = __hip_atomic_load(hs + s * 256 + tid,
                                                    __ATOMIC_RELAXED,
                                                    __HIP_MEMORY_SCOPE_AGENT);
                    unsigned long long bad = 0;
                    #pragma unroll
                    for (int s = 0; s < 16; ++s) bad |= (hv64[s] ^ want) & tagmask;
                    if (__all(bad == 0)) break;
                }
            }
        }

        // (3) unpack h -> LDS planes (lane stride 1 u32: conflict-free)
        {
            unsigned int* lh_hi = (unsigned int*)lh;
            unsigned int* lh_lo = lh_hi + 4096;
            #pragma unroll
            for (int s = 0; s < 16; ++s) {
                const int o = s * 256 + tid;
                const unsigned int w0 = (unsigned int)hv64[s];
                const unsigned int w1 = (unsigned int)(hv64[s] >> 32);
                lh_hi[o] = (w0 & 0xffffu) | (w1 << 16);
                lh_lo[o] = (w0 >> 16)     | (w1 & 0xffff0000u);
            }
        }
        __syncthreads();   // the step's ONLY barrier: h LDS + E(t+1) staged

        // (4) h MFMAs (K=512)
        #pragma unroll
        for (int kk = 0; kk < 16; ++kk) {
            v8s ah = *(const v8s*)(lh + (kk * 64 + l) * 8);
            v8s al = *(const v8s*)(lh + 8192 + (kk * 64 + l) * 8);
            acc0 = __builtin_amdgcn_mfma_f32_16x16x32_bf16(ah, bhi[kk], acc0, 0, 0, 0);
            acc1 = __builtin_amdgcn_mfma_f32_16x16x32_bf16(ah, blo[kk], acc1, 0, 0, 0);
            acc2 = __builtin_amdgcn_mfma_f32_16x16x32_bf16(al, bhi[kk], acc2, 0, 0, 0);
        }

        // (5) epilogue: tanh, split, embed write tag in bit16 of every word,
        //     transpose via LDS scratch, 4 fully coalesced publishes.
        if (t < L_SEQ - 1) {
            const unsigned int wtag = (unsigned int)(((t + 1) >> 1) & 1) << 16;
            unsigned int* myt = tp[w];
            #pragma unroll
            for (int r = 0; r < 4; ++r) {
                const int m = q * 4 + r;             // C/D: row=(lane>>4)*4+r
                const float pre = acc0[r] + acc1[r] + acc2[r] + bias;
                const float hv = tanh_fast(pre);
                short hi, lo; split_hilo(hv, hi, lo);
                unsigned int word = (unsigned int)(unsigned short)hi
                                  | ((unsigned int)(unsigned short)lo << 16);
                word = (word & 0xFFFEFFFFu) | wtag;   // lo-LSB := epoch tag
                myt[(m + 16 * (lo16 >> 3)) * 8 + (lo16 & 7)] = word;
            }
            asm volatile("s_waitcnt lgkmcnt(0)" ::: "memory");
            #pragma unroll
            for (int k = 0; k < 4; ++k) {
                const unsigned int val = tp[w][k * 64 + l];
                unsigned int* p = exdst + region + k * 64 + l;
                if (FLAVOR == 1)      st_sc0g(p, val);
                else if (FLAVOR == 2) at_xchg32(p, val);
                else                  st_sc1(p, val);
            }
        } else {
            #pragma unroll
            for (int r = 0; r < 4; ++r) {
                const int m = q * 4 + r;
                const float pre = acc0[r] + acc1[r] + acc2[r] + bias;
                out[(long)(nbase + m) * HID + hcol] = tanh_fast(pre);
            }
        }
    }
}

__global__ __launch_bounds__(256, 1) void rnn_scan8(
    const float* __restrict__ Whh,
    const float* __restrict__ Whh_b,
    const float* __restrict__ Wxh,
    const float* __restrict__ Wxh_b,
    const short* __restrict__ Esw,
    unsigned int* __restrict__ ex,
    unsigned int* __restrict__ ctl,   // may be nullptr -> slow path
    float* __restrict__ out)
{
    const int bid = blockIdx.x;
    const int g   = bid & 15;    // group
    const int j   = bid >> 4;    // member 0..7
    const int tid = threadIdx.x;

    __shared__ short ldsbuf[49152];          // h dbuf 64 KB + E dbuf 32 KB
    __shared__ unsigned int tp[4][256];      // 4 KB transpose scratch
    __shared__ int s_flavor;

    // ---- runtime same-XCD detection + two capability handshakes ----------
    // All unbounded spins use the R0-proven sc1 flavor; capability probes are
    // budget-bounded (deterministic fall-through). Vote = AND of capability
    // masks across the 8 members -> unanimous flavor choice.
    if (tid == 0) {
        int flavor = 0;
        if (ctl != nullptr) {
            unsigned int* det  = ctl;         // [128] xcc ids     (init 0xFF)
            unsigned int* tokA = ctl + 128;   // [128] A round 1   (init 0xFF)
            unsigned int* tokB = ctl + 256;   // [128] A round 2   (init 0xFF)
            unsigned int* prm  = ctl + 384;   // [128] A primed    (init 0xFF)
            unsigned int* vot  = ctl + 512;   // [128] votes       (init 0xFF)
            unsigned int* tokC = ctl + 640;   // [128] B round 1   (init 0xFF)
            unsigned int* tokD = ctl + 768;   // [128] B round 2   (init 0xFF)
            unsigned int* prm2 = ctl + 896;   // [128] B primed    (init 0xFF)
            unsigned int xcc;
            asm volatile("s_getreg_b32 %0, hwreg(HW_REG_XCC_ID)" : "=s"(xcc));
            st_sc1(det + bid, 0x100u | (xcc & 0xffu));
            unsigned int ids[8];
            for (int jj = 0; jj < 8; ++jj) {
                unsigned int v;
                do { v = ld_sc1(det + jj * 16 + g); } while (v == 0xFFFFFFFFu);
                ids[jj] = v;
            }
            bool same = true;
            for (int jj = 1; jj < 8; ++jj) same &= (ids[jj] == ids[0]);
            unsigned int mask = 1;
            if (same) {
                // ---- handshake A: sc0 store -> sc0 load (tests FLAVOR 1) --
                // prime: pull token lines toward this side as stale copies;
                // if sc0 loads don't bypass stale caches, A fails (bounded).
                for (int jj = 0; jj < 8; ++jj) {
                    (void)ld_sc0(tokA + jj * 16 + g);
                    (void)ld_sc0(tokB + jj * 16 + g);
                }
                st_sc1(prm + bid, 1u);
                for (int jj = 0; jj < 8; ++jj)
                    while (ld_sc1(prm + jj * 16 + g) == 0xFFFFFFFFu) {}
                int budget = 2048; bool okA = true;
                st_sc0g(tokA + bid, 0xA5A5A5A5u);
                for (int jj = 0; jj < 8; ++jj) {
                    unsigned int v;
                    do { v = ld_sc0(tokA + jj * 16 + g); }
                    while (v != 0xA5A5A5A5u && --budget > 0);
                    okA &= (v == 0xA5A5A5A5u);
                }
                st_sc0g(tokB + bid, 0x5A5A5A5Au);
                for (int jj = 0; jj < 8 && okA; ++jj) {
                    unsigned int v;
                    do { v = ld_sc0(tokB + jj * 16 + g); }
                    while (v != 0x5A5A5A5Au && --budget > 0);
                    okA &= (v == 0x5A5A5A5Au);
                }
                // ---- handshake B: L2-local atomics (tests FLAVOR 2) -------
                // prime: atomics pull lines into THIS L2; cross-XCD they then
                // read stale forever (bounded) -> deterministic failure.
                for (int jj = 0; jj < 8; ++jj) {
                    (void)at_or32(tokC + jj * 16 + g);
                    (void)at_or32(tokD + jj * 16 + g);
                }
                st_sc1(prm2 + bid, 1u);
                for (int jj = 0; jj < 8; ++jj)
                    while (ld_sc1(prm2 + jj * 16 + g) == 0xFFFFFFFFu) {}
                int budget2 = 2048; bool okB = true;
                at_xchg32(tokC + bid, 0xC3C3C3C3u);
                for (int jj = 0; jj < 8; ++jj) {
                    unsigned int v;
                    do { v = at_or32(tokC + jj * 16 + g); }
                    while (v != 0xC3C3C3C3u && --budget2 > 0);
                    okB &= (v == 0xC3C3C3C3u);
                }
                at_xchg32(tokD + bid, 0x3C3C3C3Cu);
                for (int jj = 0; jj < 8 && okB; ++jj) {
                    unsigned int v;
                    do { v = at_or32(tokD + jj * 16 + g); }
                    while (v != 0x3C3C3C3Cu && --budget2 > 0);
                    okB &= (v == 0x3C3C3C3Cu);
                }
                mask = 1u | (okB ? 2u : 0u) | (okA ? 4u : 0u);
            }
            // ---- vote: AND of capability masks, pick highest common ------
            st_sc1(vot + bid, 0x100u | mask);
            unsigned int common = 7u;
            for (int jj = 0; jj < 8; ++jj) {
                unsigned int v;
                do { v = ld_sc1(vot + jj * 16 + g); } while (v == 0xFFFFFFFFu);
                common &= v;
            }
            flavor = (common & 4u) ? 1 : (common & 2u) ? 2 : 0;
        }
        s_flavor = flavor;
    }
    __syncthreads();

    if (s_flavor == 1)
        scan_loop<1>(Whh, Whh_b, Wxh, Wxh_b, Esw, ex, out, ldsbuf, tp, g, j, tid);
    else if (s_flavor == 2)
        scan_loop<2>(Whh, Whh_b, Wxh, Wxh_b, Esw, ex, out, ldsbuf, tp, g, j, tid);
    else
        scan_loop<0>(Whh, Whh_b, Wxh, Wxh_b, Esw, ex, out, ldsbuf, tp, g, j, tid);
}

// ---------------------------------------------------------------------------
extern "C" void kernel_launch(void* const* d_in, const int* in_sizes, int n_in,
                              void* d_out, int out_size, void* d_ws, size_t ws_size,
                              hipStream_t stream) {
    const int*   X     = (const int*)d_in[0];
    const float* emb   = (const float*)d_in[1];
    const float* Whh   = (const float*)d_in[2];
    const float* Whh_b = (const float*)d_in[3];
    const float* Wxh   = (const float*)d_in[4];
    const float* Wxh_b = (const float*)d_in[5];

    char* ws = (char*)d_ws;
    short*        Esw = (short*)ws;
    unsigned int* ex  = (unsigned int*)(ws + ESW_BYTES);
    unsigned int* ctl = nullptr;
    if (ws_size >= ESW_BYTES + EX_BYTES + CTL_BYTES)
        ctl = (unsigned int*)(ws + ESW_BYTES + EX_BYTES);

    // parity 0 := 0x00 (h(0)=0, tag 0 matches t=0 immediately);
    // parity 1 := 0xFF (tag 1 blocks t=1 until step-0 data lands);
    // ctl      := 0xFF (detect/handshake slots empty).
    hipMemsetAsync(ex, 0x00, EX_BYTES / 2, stream);
    hipMemsetAsync((char*)ex + EX_BYTES / 2, 0xFF, EX_BYTES / 2, stream);
    if (ctl) hipMemsetAsync(ctl, 0xFF, CTL_BYTES, stream);

    esw_build<<<dim3(NGROUPS * L_SEQ), dim3(256), 0, stream>>>(X, emb, Esw);
    rnn_scan8<<<dim3(NGROUPS * GWGS), dim3(256), 0, stream>>>(
        Whh, Whh_b, Wxh, Wxh_b, Esw, ex, ctl, (float*)d_out);
}

// Round 7
// 1726.354 us; speedup vs baseline: 1.4315x; 1.1951x over previous
//
#include <hip/hip_runtime.h>
#include <hip/hip_bf16.h>
#include <math.h>

// Problem constants
#define N_B    256   // batch
#define L_SEQ  512   // sequence length
#define HID    512   // hidden
#define EMB_D  256   // embedding dim

// 16 groups x 16 batch rows; 8 wgs/group each owning 64 Whh cols.
#define NGROUPS 16
#define GWGS    8

// Workspace: E_sw + exchange (parity dbuf) + tag array (128 KB).
#define ESW_SHORTS_PER_BLK 8192   // per (g,t): 2 planes x 8 kk x 64 lanes x 8 = 16 KB
#define ESW_BYTES  ((size_t)NGROUPS * L_SEQ * ESW_SHORTS_PER_BLK * 2)  // 134,217,728
#define EX_UINTS_PER_SLOT (16 * HID)                                   // 8192 = 32 KB
#define EX_BYTES   ((size_t)2 * NGROUPS * EX_UINTS_PER_SLOT * 4)       // 1 MB
// tag array: [2 parity][16 group][32 (member*4+wave)] x 32-uint stride (128 B
// per tag -> private LLC sector, no false sharing). 128 KB total.
#define TAG_STRIDE 32
#define TAG_UINTS  ((size_t)2 * NGROUPS * 32 * TAG_STRIDE)             // 32768
#define TAG_BYTES  (TAG_UINTS * 4)                                     // 131072

typedef short v8s __attribute__((ext_vector_type(8)));   // 8 bf16 MFMA A/B frag
typedef float v4f __attribute__((ext_vector_type(4)));   // MFMA C/D frag

static __device__ __forceinline__ unsigned short bf_bits(__hip_bfloat16 h) {
    union { __hip_bfloat16 b; unsigned short u; } c; c.b = h; return c.u;
}
static __device__ __forceinline__ void split_hilo(float v, short& hi, short& lo) {
    const __hip_bfloat16 h = __float2bfloat16(v);
    hi = (short)bf_bits(h);
    lo = (short)bf_bits(__float2bfloat16(v - __bfloat162float(h)));
}
static __device__ __forceinline__ void cvt8_hilo(const float* __restrict__ p,
                                                 v8s& hi, v8s& lo) {
    #pragma unroll
    for (int i = 0; i < 8; ++i) { short h, l; split_hilo(p[i], h, l); hi[i] = h; lo[i] = l; }
}
// async global->LDS, 16 B per lane; LDS dest = wave-uniform base + lane*16
static __device__ __forceinline__ void gl_lds16(const short* g, short* l) {
    __builtin_amdgcn_global_load_lds(
        (const __attribute__((address_space(1))) unsigned int*)g,
        (__attribute__((address_space(3))) unsigned int*)l, 16, 0, 0);
}
// fast tanh: 1 - 2/(exp(2x)+1); v_exp_f32-based, ~1e-7 abs err
static __device__ __forceinline__ float tanh_fast(float x) {
    const float z = __expf(2.0f * x);
    return 1.0f - 2.0f / (z + 1.0f);
}
// sc1 (device scope via LLC): correct for any WG->XCD placement (R0-proven).
static __device__ __forceinline__ void st_sc1(unsigned int* p, unsigned int v) {
    __hip_atomic_store(p, v, __ATOMIC_RELAXED, __HIP_MEMORY_SCOPE_AGENT);
}
static __device__ __forceinline__ unsigned int ld_sc1(const unsigned int* p) {
    return __hip_atomic_load(p, __ATOMIC_RELAXED, __HIP_MEMORY_SCOPE_AGENT);
}

// ---------------------------------------------------------------------------
// Precompute E_sw (unchanged, correctness-proven).
// ---------------------------------------------------------------------------
__global__ __launch_bounds__(256) void esw_build(
    const int* __restrict__ X, const float* __restrict__ emb,
    short* __restrict__ Esw)
{
    const int bid = blockIdx.x;           // g*512 + t
    const int g = bid >> 9, t = bid & 511;
    short* base = Esw + (size_t)bid * ESW_SHORTS_PER_BLK;
    #pragma unroll
    for (int h = 0; h < 2; ++h) {
        const int f    = threadIdx.x + h * 256;   // frag id 0..511
        const int kk   = f >> 6, lane = f & 63;
        const int m    = lane & 15, qp = lane >> 4;
        const int idx  = X[(g * 16 + m) * L_SEQ + t];
        const float* src = emb + (size_t)idx * EMB_D + kk * 32 + qp * 8;
        v8s hi8, lo8;
        cvt8_hilo(src, hi8, lo8);
        short* d = base + (size_t)(kk * 64 + lane) * 8;
        *(v8s*)d          = hi8;
        *(v8s*)(d + 4096) = lo8;
    }
}

// ---------------------------------------------------------------------------
// Persistent RNN scan = R0 structure + TAG-GATED poll. All memory ops are
// the R0-proven sc1 flavor; the only change is WHAT the spin reads:
//   publish: 4 coalesced sc1 data stores (tagged per-word epoch bit, as R0)
//            then ONE sc1 tag store per wave: tag[(t+1)&1][g][j][w] := t+1.
//   consume: spin on 32 tag dwords (128 B/WG/iter, lanes 0-31 one tag each)
//            until all == t; then run R0's epoch-validated bulk pass, which
//            usually exits in 1 iteration and ABSORBS any tag-before-data
//            race (relaxed sc1 gives no order; validation gives correctness).
// Rationale: R0's spin body was 32 KB/WG/iter -> ~4 MB/poll-round across 128
// WGs, self-inflating LLC RTT and quantizing detection at ~1000+ cy. Tags
// cut poll traffic ~256x and shrink the detect quantum.
// Deadlock-free: a consumer spinning at gate t implies some member hasn't
// published tag t => nobody can pass gate t+1 => no ==t tag slot can be
// overwritten with t+2 while anyone still needs it. Tags memset per launch:
// parity-0 = 0 passes t=0 instantly; parity-1 = 0xFF blocks t=1.
// WAR at distance 2 unchanged: poll(t) pass => all published end-of-(t-1)
// => all completed their (t-1) reads of the buffer being overwritten.
// ---------------------------------------------------------------------------
__global__ __launch_bounds__(256, 1) void rnn_scan11(
    const float* __restrict__ Whh,
    const float* __restrict__ Whh_b,
    const float* __restrict__ Wxh,
    const float* __restrict__ Wxh_b,
    const short* __restrict__ Esw,
    unsigned int* __restrict__ ex,
    unsigned int* __restrict__ tags,
    float* __restrict__ out)
{
    const int bid  = blockIdx.x;
    const int g    = bid & 15;    // group (members share XCD via %8 heuristic)
    const int j    = bid >> 4;    // member 0..7
    const int tid  = threadIdx.x;
    const int w    = tid >> 6;
    const int l    = tid & 63;
    const int lo16 = l & 15;
    const int q    = l >> 4;
    const int cbase = j * 64 + w * 16;
    const int nbase = g * 16;

    // LDS: h dbuf 64 KB + E dbuf 32 KB + 4 KB transpose scratch = 100 KB
    __shared__ short ldsbuf[49152];
    __shared__ unsigned int tp[4][256];
    short* lds_h = ldsbuf;          // P*16384 + plane*8192 + (kk*64+l)*8 + i
    short* lds_e = ldsbuf + 32768;  // P*8192  + plane*4096 + (kk*64+l)*8 + i

    // Whh 64-col slice as hi/lo bf16 B-frags
    v8s bhi[16], blo[16];
    {
        const float* wp = Whh + (long)(cbase + lo16) * HID + q * 8;
        #pragma unroll
        for (int kk = 0; kk < 16; ++kk) cvt8_hilo(wp + kk * 32, bhi[kk], blo[kk]);
    }
    // Wxh 64-col slice
    v8s xhi[8], xlo[8];
    {
        const float* wp = Wxh + (long)(cbase + lo16) * EMB_D + q * 8;
        #pragma unroll
        for (int kk = 0; kk < 8; ++kk) cvt8_hilo(wp + kk * 32, xhi[kk], xlo[kk]);
    }
    const int hcol = cbase + lo16;
    const float bias = Whh_b[hcol] + Wxh_b[hcol];

    // wave's contiguous 1 KB publish region (uints): kk_s = 2j + (w>>1),
    // covering q2 = 2(w&1)..2(w&1)+1.
    const int region = (2 * j + (w >> 1)) * 512 + (w & 1) * 256;

    unsigned int* ex0 = ex + (size_t)g * EX_UINTS_PER_SLOT;              // parity 0
    unsigned int* ex1 = ex + (size_t)(NGROUPS + g) * EX_UINTS_PER_SLOT;  // parity 1
    const short* esrc = Esw + (size_t)(g * 512) * ESW_SHORTS_PER_BLK;

    // my tag slot (written by lane 0 of each wave); consumer mapping below
    unsigned int* mytag0 = tags + ((size_t)(0 * NGROUPS + g) * 32 + (j * 4 + w)) * TAG_STRIDE;
    unsigned int* mytag1 = tags + ((size_t)(1 * NGROUPS + g) * 32 + (j * 4 + w)) * TAG_STRIDE;

    // preamble: stage E(0) into parity-0 E buffer; barrier makes it visible
    #pragma unroll
    for (int c = 0; c < 4; ++c)
        gl_lds16(esrc + (w * 4 + c) * 512 + l * 8, lds_e + (w * 4 + c) * 512);
    __syncthreads();

    for (int t = 0; t < L_SEQ; ++t) {
        const int P = t & 1;
        short* lh = lds_h + P * 16384;
        short* le = lds_e + P * 8192;
        unsigned int* exsrc = P ? ex1 : ex0;
        unsigned int* exdst = P ? ex0 : ex1;

        // (0) prefetch E(t+1) into other parity (drained by this step's barrier)
        if (t + 1 < L_SEQ) {
            const short* eb = esrc + (size_t)(t + 1) * ESW_SHORTS_PER_BLK;
            short* leN = lds_e + (P ^ 1) * 8192;
            #pragma unroll
            for (int c = 0; c < 4; ++c)
                gl_lds16(eb + (w * 4 + c) * 512 + l * 8, leN + (w * 4 + c) * 512);
        }

        // (1) E MFMAs (peer-independent; run while peers' h data propagates)
        v4f acc0 = {0,0,0,0}, acc1 = {0,0,0,0}, acc2 = {0,0,0,0};
        #pragma unroll
        for (int kk = 0; kk < 8; ++kk) {
            v8s ah = *(const v8s*)(le + (kk * 64 + l) * 8);
            v8s al = *(const v8s*)(le + 4096 + (kk * 64 + l) * 8);
            acc0 = __builtin_amdgcn_mfma_f32_16x16x32_bf16(ah, xhi[kk], acc0, 0, 0, 0);
            acc1 = __builtin_amdgcn_mfma_f32_16x16x32_bf16(ah, xlo[kk], acc1, 0, 0, 0);
            acc2 = __builtin_amdgcn_mfma_f32_16x16x32_bf16(al, xhi[kk], acc2, 0, 0, 0);
        }

        // (2a) tag gate: 128 B/WG per iteration instead of 32 KB. Lane p
        //      (p<32) watches member p>>2, wave p&3; upper lanes duplicate.
        {
            const int who = l & 31;
            const unsigned int* tg =
                tags + ((size_t)(P * NGROUPS + g) * 32 + who) * TAG_STRIDE;
            for (;;) {
                const unsigned int tv = ld_sc1(tg);
                if (__all(tv == (unsigned int)t)) break;
            }
        }

        // (2b) R0's epoch-validated bulk pass (unchanged semantics; now
        //      usually a single iteration — it also absorbs any
        //      tag-before-data arrival from the relaxed sc1 ordering).
        unsigned long long hv64[16];
        {
            const unsigned long long* hs = (const unsigned long long*)exsrc;
            const unsigned long long tagmask = 0x0001000000010000ull;
            const unsigned long long want = ((t >> 1) & 1) ? tagmask : 0ull;
            for (;;) {
                #pragma unroll
                for (int s = 0; s < 16; ++s)
                    hv64[s] = __hip_atomic_load(hs + s * 256 + tid,
                                                __ATOMIC_RELAXED,
                                                __HIP_MEMORY_SCOPE_AGENT);
                unsigned long long bad = 0;
                #pragma unroll
                for (int s = 0; s < 16; ++s) bad |= (hv64[s] ^ want) & tagmask;
                if (__all(bad == 0)) break;
            }
        }

        // (3) unpack h -> LDS planes (lane stride 1 u32: conflict-free)
        {
            unsigned int* lh_hi = (unsigned int*)lh;
            unsigned int* lh_lo = lh_hi + 4096;
            #pragma unroll
            for (int s = 0; s < 16; ++s) {
                const int o = s * 256 + tid;
                const unsigned int w0 = (unsigned int)hv64[s];
                const unsigned int w1 = (unsigned int)(hv64[s] >> 32);
                lh_hi[o] = (w0 & 0xffffu) | (w1 << 16);
                lh_lo[o] = (w0 >> 16)     | (w1 & 0xffff0000u);
            }
        }
        __syncthreads();   // the step's ONLY barrier: h LDS + E(t+1) staged

        // (4) h MFMAs (K=512)
        #pragma unroll
        for (int kk = 0; kk < 16; ++kk) {
            v8s ah = *(const v8s*)(lh + (kk * 64 + l) * 8);
            v8s al = *(const v8s*)(lh + 8192 + (kk * 64 + l) * 8);
            acc0 = __builtin_amdgcn_mfma_f32_16x16x32_bf16(ah, bhi[kk], acc0, 0, 0, 0);
            acc1 = __builtin_amdgcn_mfma_f32_16x16x32_bf16(ah, blo[kk], acc1, 0, 0, 0);
            acc2 = __builtin_amdgcn_mfma_f32_16x16x32_bf16(al, bhi[kk], acc2, 0, 0, 0);
        }

        // (5) epilogue: tanh, split, embed epoch bit in bit16, transpose via
        //     LDS scratch, 4 coalesced sc1 data stores, then the tag store.
        if (t < L_SEQ - 1) {
            const unsigned int wtag = (unsigned int)(((t + 1) >> 1) & 1) << 16;
            unsigned int* myt = tp[w];
            #pragma unroll
            for (int r = 0; r < 4; ++r) {
                const int m = q * 4 + r;             // C/D: row=(lane>>4)*4+r
                const float pre = acc0[r] + acc1[r] + acc2[r] + bias;
                const float hv = tanh_fast(pre);
                short hi, lo; split_hilo(hv, hi, lo);
                unsigned int word = (unsigned int)(unsigned short)hi
                                  | ((unsigned int)(unsigned short)lo << 16);
                word = (word & 0xFFFEFFFFu) | wtag;   // lo-LSB := epoch bit
                myt[(m + 16 * (lo16 >> 3)) * 8 + (lo16 & 7)] = word;
            }
            asm volatile("s_waitcnt lgkmcnt(0)" ::: "memory");
            #pragma unroll
            for (int k = 0; k < 4; ++k) {
                const unsigned int val = myt[k * 64 + l];
                st_sc1(exdst + region + k * 64 + l, val);
            }
            // tag := t+1 (program-order after data; any reordering at the
            // LLC is absorbed by the consumer's epoch validation)
            if (l == 0)
                st_sc1(((t + 1) & 1) ? mytag1 : mytag0, (unsigned int)(t + 1));
        } else {
            #pragma unroll
            for (int r = 0; r < 4; ++r) {
                const int m = q * 4 + r;
                const float pre = acc0[r] + acc1[r] + acc2[r] + bias;
                out[(long)(nbase + m) * HID + hcol] = tanh_fast(pre);
            }
        }
    }
}

// ---------------------------------------------------------------------------
extern "C" void kernel_launch(void* const* d_in, const int* in_sizes, int n_in,
                              void* d_out, int out_size, void* d_ws, size_t ws_size,
                              hipStream_t stream) {
    const int*   X     = (const int*)d_in[0];
    const float* emb   = (const float*)d_in[1];
    const float* Whh   = (const float*)d_in[2];
    const float* Whh_b = (const float*)d_in[3];
    const float* Wxh   = (const float*)d_in[4];
    const float* Wxh_b = (const float*)d_in[5];

    char* ws = (char*)d_ws;
    short*        Esw  = (short*)ws;
    unsigned int* ex   = (unsigned int*)(ws + ESW_BYTES);
    unsigned int* tags = (unsigned int*)(ws + ESW_BYTES + EX_BYTES);
    // tags region (128 KB at ESW+EX) proven allocated/writable in R3's run.

    // parity 0 := 0x00 (h(0)=0, epoch bit 0 matches t=0 instantly);
    // parity 1 := 0xFF (epoch bit 1 blocks t=1 until real step-0 data).
    hipMemsetAsync(ex, 0x00, EX_BYTES / 2, stream);
    hipMemsetAsync((char*)ex + EX_BYTES / 2, 0xFF, EX_BYTES / 2, stream);
    // tag parity 0 := 0 (== t=0, gate opens instantly);
    // tag parity 1 := 0xFF (!= 1, gate blocks t=1 until published).
    hipMemsetAsync(tags, 0x00, TAG_BYTES / 2, stream);
    hipMemsetAsync((char*)tags + TAG_BYTES / 2, 0xFF, TAG_BYTES / 2, stream);

    esw_build<<<dim3(NGROUPS * L_SEQ), dim3(256), 0, stream>>>(X, emb, Esw);
    rnn_scan11<<<dim3(NGROUPS * GWGS), dim3(256), 0, stream>>>(
        Whh, Whh_b, Wxh, Wxh_b, Esw, ex, tags, (float*)d_out);
}